// Round 14
// baseline (256.288 us; speedup 1.0000x reference)
//
#include <hip/hip_runtime.h>
#include <hip/hip_bf16.h>

typedef unsigned short u16;
typedef __attribute__((ext_vector_type(4))) int   int4v;
typedef __attribute__((ext_vector_type(4))) unsigned int uint4v;
typedef __attribute__((ext_vector_type(4))) unsigned short ushort4v;
typedef __attribute__((ext_vector_type(4))) float floatx4;
typedef __attribute__((ext_vector_type(8))) short bf16x8;
typedef _Float16 half8 __attribute__((ext_vector_type(8)));
typedef _Float16 half2v __attribute__((ext_vector_type(2)));

#define LRELU_NS 0.01f
#define SK 264   // LDS k-stride (u16 units): 256 + 8 pad, 16B-aligned rows

__device__ __forceinline__ float bitsToF(unsigned int b) {
    union { unsigned int u; float f; } v; v.u = b << 16; return v.f;
}
__device__ __forceinline__ u16 f2bf(float f) {
    __hip_bfloat16 h = __float2bfloat16(f);
    return *reinterpret_cast<u16*>(&h);
}
// 2-op leaky relu (f32): max(x, 0.01x) — exact for all finite x
__device__ __forceinline__ float lrelu(float v) {
    return fmaxf(v, LRELU_NS * v);
}
__device__ __forceinline__ u16 ldW(const void* p, int i, int isF32) {
    return isF32 ? f2bf(((const float*)p)[i]) : ((const u16*)p)[i];
}
__device__ __forceinline__ float ldF(const void* p, int i, int isF32) {
    return isF32 ? ((const float*)p)[i]
                 : bitsToF((unsigned int)((const u16*)p)[i]);
}
// float -> fp16 bits (native _Float16 cast = round-to-nearest-even)
__device__ __forceinline__ u16 f2h_bits(float f) {
    union { _Float16 h; u16 u; } v; v.h = (_Float16)f; return v.u;
}
// load -> fp16 bits (for the f16 pair path)
__device__ __forceinline__ u16 ldWh(const void* p, int i, int isF32) {
    float f = isF32 ? ((const float*)p)[i]
                    : bitsToF((unsigned int)((const u16*)p)[i]);
    return f2h_bits(f);
}
__device__ __forceinline__ half2v u2h2(unsigned int x) {
    union { unsigned int u; half2v h; } v; v.u = x; return v.h;
}
__device__ __forceinline__ unsigned int h22u(half2v x) {
    union { half2v h; unsigned int u; } v; v.h = x; return v.u;
}

// dtype probe (verified) — all threads of the block must call.
__device__ __forceinline__ int computeIsF32(const u16* y, int* cnt, int t) {
    if (t == 0) *cnt = 0;
    __syncthreads();
    if (t < 256) {
        u16 v = y[2 * t];
        int e = (v >> 7) & 0xFF;
        if (v == 0 || (e >= 96 && e < 160)) atomicAdd(cnt, 1);
    }
    __syncthreads();
    return (*cnt < 192) ? 1 : 0;
}

// ---------------------------------------------------------------------------
// Kernel 1: pack — verbatim R0 (verified).
// ---------------------------------------------------------------------------
__global__ __launch_bounds__(256) void pack_kernel(
    const void* __restrict__ yhat,
    const void* __restrict__ Ws1, const void* __restrict__ Wc1,
    const void* __restrict__ Wb1, const void* __restrict__ Ws2,
    const void* __restrict__ Wc2,
    const void* __restrict__ bs1, const void* __restrict__ bc1,
    const void* __restrict__ bb1, const void* __restrict__ bs2,
    const void* __restrict__ bc2, const void* __restrict__ bb2,
    u16* __restrict__ WallT, u16* __restrict__ W2T, float* __restrict__ biasF)
{
    __shared__ int fcnt;
    const int bid = blockIdx.x, t = threadIdx.x;
    const int isF32 = computeIsF32((const u16*)yhat, &fcnt, t);
    if (bid < 64) {
        __shared__ u16 tile[64][65];
        const int c0 = (bid & 15) * 64;      // col-tile in [0,1024)
        const int k0 = (bid >> 4) * 64;      // k-tile in [0,256)
        const void* src; int coff; int roff = 0;
        if (c0 < 256)      { src = Ws1; coff = c0; }
        else if (c0 < 512) { src = Wc1; coff = c0 - 256; }
        else if (c0 < 768) { src = Wb1; coff = c0 - 512; }
        else               { src = Wb1; coff = c0 - 768; roff = 256; }
        const int cc = t & 63, kk0 = t >> 6;
        #pragma unroll
        for (int i = 0; i < 16; ++i) {
            int kk = kk0 + i * 4;
            tile[kk][cc] = ldW(src, (k0 + kk + roff) * 256 + coff + cc, isF32);
        }
        __syncthreads();
        const int kk2 = t & 63, cc0 = t >> 6;
        #pragma unroll
        for (int i = 0; i < 16; ++i) {
            int cc2 = cc0 + i * 4;
            WallT[(c0 + cc2) * 256 + (k0 + kk2)] = tile[kk2][cc2];
        }
    } else if (bid < 128) {
        int e2 = (bid - 64) * 256 + t;       // < 16384
        int c = e2 >> 8, k = e2 & 255;
        u16 v = 0;
        if (c < 40)                 v = ldW(Ws2, k * 40 + c, isF32);
        else if (c >= 48 && c < 53) v = ldW(Wc2, k * 5 + (c - 48), isF32);
        W2T[c * 256 + k] = v;
    } else {
        int idx = (bid - 128) * 256 + t;     // < 1024
        float v = 0.f;
        if (idx < 256)       v = ldF(bs1, idx, isF32);
        else if (idx < 512)  v = ldF(bc1, idx - 256, isF32);
        else if (idx < 768)  v = ldF(bb1, idx - 512, isF32);
        else if (idx < 808)  v = ldF(bs2, idx - 768, isF32);
        else if (idx < 813)  v = ldF(bc2, idx - 808, isF32);
        else if (idx >= 816 && idx < 821) v = ldF(bb2, idx - 816, isF32);
        biasF[idx] = v;
    }
}

// ---------------------------------------------------------------------------
// Kernel 2: fused — heterogeneous blocks, 512 threads each. NO X staging:
// L1 MFMA A-frags load directly from global (16B/lane; X tiles are L1/L2
// resident). A-frag VALUES bit-identical to the R10-verified staged path
// (same f2bf cvt; bonds rows 40..47 zeroed via clamp+select).
//   bid in [0,512):   bonds — LDS = P1L+P2L+WsB = 53,328 B, ONE barrier.
//   bid in [512,832): heads — LDS = Hb = 33,792 B, ONE barrier.
// Union 53,328 B -> 3 blocks/CU (24 waves, was 2/16 in R10). No aliasing,
// no register holding (R12's serialization lesson). Everything after the
// A-frag source is verbatim R10.
// ---------------------------------------------------------------------------
union SharedHB {
    struct { u16 P1L[48 * SK]; u16 P2L[48 * SK]; u16 WsB[5 * 264]; } bd; // 53,328 B
    struct { u16 Hb[64 * SK]; } hd;                                      // 33,792 B
};

__global__ __launch_bounds__(512) void fused_kernel(
    const void* __restrict__ Xv, const u16* __restrict__ WallT,
    const u16* __restrict__ W2T, const void* __restrict__ Wb2,
    const float* __restrict__ biasF, void* __restrict__ outv)
{
    __shared__ SharedHB sh;
    __shared__ int fcnt;
    const int t = threadIdx.x;
    const int bid = blockIdx.x;
    const int isF32 = computeIsF32((const u16*)Xv, &fcnt, t);

    const int w = t >> 6, l = t & 63;
    const int ml = l & 15, kq = l >> 4, r0 = kq * 4;

    if (bid < 512) {
        // =================== bonds body ===================
        const int b = bid >> 1;            // molecule
        const int h = bid & 1;             // job half

        // Wb2[256][5] -> WsB[c][k] fp16, c<5
        #pragma unroll
        for (int s = 0; s < 3; ++s) {
            int e2 = t + s * 512;                  // < 1536
            if (e2 < 1280) {
                int c = e2 >> 8, k = e2 & 255;
                sh.bd.WsB[c * 264 + k] = ldWh(Wb2, k * 5 + c, isF32);
            }
        }

        // A-frag from global: row = i*16+ml of molecule b; rows >=40 -> zero.
        auto ldAb = [&](int i, int k0) -> bf16x8 {
            const int row = i * 16 + ml;
            const int rc = (row < 40) ? row : 39;   // clamp (in-bounds), zero below
            bf16x8 a;
            if (isF32) {
                const float* fp = (const float*)Xv + ((size_t)b * 40 + rc) * 256 + k0;
                floatx4 f0 = *(const floatx4*)fp;
                floatx4 f1 = *(const floatx4*)(fp + 4);
                a[0] = (short)f2bf(f0[0]); a[1] = (short)f2bf(f0[1]);
                a[2] = (short)f2bf(f0[2]); a[3] = (short)f2bf(f0[3]);
                a[4] = (short)f2bf(f1[0]); a[5] = (short)f2bf(f1[1]);
                a[6] = (short)f2bf(f1[2]); a[7] = (short)f2bf(f1[3]);
            } else {
                a = *(const bf16x8*)((const u16*)Xv + ((size_t)b * 40 + rc) * 256 + k0);
            }
            if (row >= 40) { bf16x8 z = {}; a = z; }
            return a;
        };

        // ---- layer 1 (R10 math, A from global): P = X @ Wb1 (+bb1 on P1) ----
        for (int n = 0; n < 4; ++n) {
            const int gc = (w + 8 * n) * 16 + ml;  // [0,512)
            floatx4 acc[3] = {};
            #pragma unroll
            for (int ks = 0; ks < 8; ++ks) {
                const int k0 = ks * 32 + kq * 8;
                bf16x8 bf = *(const bf16x8*)&WallT[(512 + gc) * 256 + k0];
                #pragma unroll
                for (int i = 0; i < 3; ++i) {
                    bf16x8 a = ldAb(i, k0);
                    acc[i] = __builtin_amdgcn_mfma_f32_16x16x32_bf16(a, bf, acc[i], 0, 0, 0);
                }
            }
            u16* dst = (gc < 256) ? sh.bd.P1L : sh.bd.P2L;
            const int col = gc & 255;
            const float bias = (gc < 256) ? biasF[512 + gc] : 0.f;   // bb1 on P1
            #pragma unroll
            for (int i = 0; i < 3; ++i)
                #pragma unroll
                for (int r = 0; r < 4; ++r)
                    dst[(i * 16 + r0 + r) * SK + col] = f2h_bits(acc[i][r] + bias);
        }
        __syncthreads();   // P + WsB visible

        // ---- symmetric-fused pair phase, packed f16 (verbatim R10) ----
        const int sel = (ml < 5) ? ml : 4;         // ml>=5 feeds discarded D cols
        half8 wf[8];
        #pragma unroll
        for (int ks = 0; ks < 8; ++ks)
            wf[ks] = *(const half8*)&sh.bd.WsB[sel * 264 + ks * 32 + kq * 8];
        const float b2x2 = 2.f * biasF[816 + ml];  // ml>=5 reads zeros (in-bounds)
        const _Float16 c001 = (_Float16)0.01f;

        // 11 (m, jt) jobs per wave; halves take alternating jobs.
        constexpr int mT[11]  = {0, 0, 0, 1, 1, 1, 2, 2, 3, 3, 4};
        constexpr int jtT[11] = {0, 1, 2, 0, 1, 2, 1, 2, 1, 2, 2};
        #pragma unroll
        for (int idx = 0; idx < 11; ++idx) {
            if ((idx & 1) != h) continue;          // block-uniform
            const int m = mT[idx], jt = jtT[idx];
            const int i = w + 8 * m;               // [0,40)
            const bool diag = (jt == (i >> 4));    // wave-uniform per job
            floatx4 acc = {};
            #pragma unroll
            for (int ks = 0; ks < 8; ++ks) {
                const int k0 = ks * 32 + kq * 8;
                const uint4v a1 = *(const uint4v*)&sh.bd.P1L[i * SK + k0];
                const uint4v a2 = *(const uint4v*)&sh.bd.P2L[i * SK + k0];
                const uint4v b1 = *(const uint4v*)&sh.bd.P1L[(jt * 16 + ml) * SK + k0];
                const uint4v b2 = *(const uint4v*)&sh.bd.P2L[(jt * 16 + ml) * SK + k0];
                union { unsigned int u[4]; half8 v; } af;
                #pragma unroll
                for (int d = 0; d < 4; ++d) {
                    const half2v tF = u2h2(a1[d]) + u2h2(b2[d]);   // v_pk_add_f16
                    const half2v tB = u2h2(b1[d]) + u2h2(a2[d]);
                    const half2v lF = __builtin_elementwise_max(tF, tF * c001);
                    const half2v lB = __builtin_elementwise_max(tB, tB * c001);
                    af.u[d] = h22u(lF + lB);
                }
                acc = __builtin_amdgcn_mfma_f32_16x16x32_f16(af.v, wf[ks], acc, 0, 0, 0);
            }
            if (ml < 5) {                          // D: row=kq*4+r -> j, col=ml -> class
                #pragma unroll
                for (int r = 0; r < 4; ++r) {
                    const int j = jt * 16 + r0 + r;
                    if (j < 40 && (!diag || j >= i)) {
                        const float v = acc[r] + b2x2;
                        const int o1 = 460800 + (b * 1600 + i * 40 + j) * 5 + ml;
                        if (isF32) ((float*)outv)[o1] = v;
                        else ((__hip_bfloat16*)outv)[o1] = __float2bfloat16(v);
                        if (!diag || j > i) {
                            const int o2 = 460800 + (b * 1600 + j * 40 + i) * 5 + ml;
                            if (isF32) ((float*)outv)[o2] = v;
                            else ((__hip_bfloat16*)outv)[o2] = __float2bfloat16(v);
                        }
                    }
                }
            }
        }
    } else {
        // =================== heads body ===================
        const int hb = bid - 512;
        const int bm0 = (hb % 160) * 64;
        const int head = hb / 160;

        // A-frag from global: row = bm0 + mt*16 + ml, always < 10240.
        auto ldAh = [&](int mt, int k0) -> bf16x8 {
            const int row = bm0 + mt * 16 + ml;
            bf16x8 a;
            if (isF32) {
                const float* fp = (const float*)Xv + (size_t)row * 256 + k0;
                floatx4 f0 = *(const floatx4*)fp;
                floatx4 f1 = *(const floatx4*)(fp + 4);
                a[0] = (short)f2bf(f0[0]); a[1] = (short)f2bf(f0[1]);
                a[2] = (short)f2bf(f0[2]); a[3] = (short)f2bf(f0[3]);
                a[4] = (short)f2bf(f1[0]); a[5] = (short)f2bf(f1[1]);
                a[6] = (short)f2bf(f1[2]); a[7] = (short)f2bf(f1[3]);
            } else {
                a = *(const bf16x8*)((const u16*)Xv + (size_t)row * 256 + k0);
            }
            return a;
        };

        // ---- layer 1 (R10 math, A from global): Hb = lrelu(X@W1 + b1) ----
        #pragma unroll
        for (int n = 0; n < 2; ++n) {
            const int ct = w + 8 * n;              // [0,16)
            floatx4 acc[4] = {};
            #pragma unroll
            for (int ks = 0; ks < 8; ++ks) {
                const int k0 = ks * 32 + kq * 8;
                bf16x8 bf = *(const bf16x8*)&WallT[(head * 256 + ct * 16 + ml) * 256 + k0];
                #pragma unroll
                for (int mt = 0; mt < 4; ++mt) {
                    bf16x8 a = ldAh(mt, k0);
                    acc[mt] = __builtin_amdgcn_mfma_f32_16x16x32_bf16(a, bf, acc[mt], 0, 0, 0);
                }
            }
            const int col = ct * 16 + ml;          // [0,256)
            const float bias = biasF[head * 256 + col];   // bs1 | bc1
            #pragma unroll
            for (int mt = 0; mt < 4; ++mt)
                #pragma unroll
                for (int r = 0; r < 4; ++r)
                    sh.hd.Hb[(mt * 16 + r0 + r) * SK + col] = f2bf(lrelu(acc[mt][r] + bias));
        }
        __syncthreads();   // Hb complete

        // ---- layer 2: waves 0..3 own M-tile w (verbatim R10) ----
        if (w < 4) {
            const int nct = (head == 0) ? 3 : 1;   // block-uniform
            const int c0  = (head == 0) ? 0 : 48;
            floatx4 acc2[3] = {};
            #pragma unroll
            for (int ks = 0; ks < 8; ++ks) {
                const int k0 = ks * 32 + kq * 8;
                bf16x8 a = *(const bf16x8*)&sh.hd.Hb[(w * 16 + ml) * SK + k0];
                #pragma unroll
                for (int j = 0; j < 3; ++j) {
                    if (j < nct) {
                        bf16x8 bf = *(const bf16x8*)&W2T[(c0 + j * 16 + ml) * 256 + k0];
                        acc2[j] = __builtin_amdgcn_mfma_f32_16x16x32_bf16(a, bf, acc2[j], 0, 0, 0);
                    }
                }
            }
            #pragma unroll
            for (int j = 0; j < 3; ++j) {
                if (j < nct) {
                    const int col = j * 16 + ml;
                    const int lim = (head == 0) ? 40 : 5;
                    if (col < lim) {
                        const float bias = biasF[(head == 0 ? 768 : 808) + col];
                        #pragma unroll
                        for (int r = 0; r < 4; ++r) {
                            const int row = bm0 + w * 16 + r0 + r;
                            const int o = (head == 0) ? row * 40 + col
                                                      : 409600 + row * 5 + col;
                            const float v = acc2[j][r] + bias;
                            if (isF32) ((float*)outv)[o] = v;
                            else ((__hip_bfloat16*)outv)[o] = __float2bfloat16(v);
                        }
                    }
                }
            }
        }
    }
}

// ---------------------------------------------------------------------------
extern "C" void kernel_launch(void* const* d_in, const int* in_sizes, int n_in,
                              void* d_out, int out_size, void* d_ws, size_t ws_size,
                              hipStream_t stream)
{
    const void* yhat = d_in[0];
    const void* Ws1  = d_in[1];
    const void* bs1  = d_in[2];
    const void* Ws2  = d_in[3];
    const void* bs2  = d_in[4];
    const void* Wc1  = d_in[5];
    const void* bc1  = d_in[6];
    const void* Wc2  = d_in[7];
    const void* bc2  = d_in[8];
    const void* Wb1  = d_in[9];
    const void* bb1  = d_in[10];
    const void* Wb2  = d_in[11];
    const void* bb2  = d_in[12];

    // workspace: 565248 bytes total (verified R0 layout)
    char* wsb = (char*)d_ws;
    float* biasF = (float*)(wsb + 4096);     // 1024 floats
    u16*   W2T   = (u16*)(wsb + 8192);       // 64*256 bf16  = 32768 B
    u16*   WallT = (u16*)(wsb + 40960);      // 1024*256 bf16 = 524288 B

    pack_kernel<<<132, 256, 0, stream>>>(yhat, Ws1, Wc1, Wb1, Ws2, Wc2,
                                         bs1, bc1, bb1, bs2, bc2, bb2,
                                         WallT, W2T, biasF);
    heads_dummy_label:;
    fused_kernel<<<832, 512, 0, stream>>>(yhat, WallT, W2T, Wb2, biasF, d_out);
}

// Round 15
// 133.093 us; speedup vs baseline: 1.9256x; 1.9256x over previous
//
#include <hip/hip_runtime.h>
#include <hip/hip_bf16.h>

typedef unsigned short u16;
typedef __attribute__((ext_vector_type(4))) int   int4v;
typedef __attribute__((ext_vector_type(4))) unsigned int uint4v;
typedef __attribute__((ext_vector_type(4))) unsigned short ushort4v;
typedef __attribute__((ext_vector_type(4))) float floatx4;
typedef __attribute__((ext_vector_type(8))) short bf16x8;
typedef _Float16 half8 __attribute__((ext_vector_type(8)));
typedef _Float16 half2v __attribute__((ext_vector_type(2)));

#define LRELU_NS 0.01f
#define SK 264   // LDS k-stride (u16 units): 256 + 8 pad, 16B-aligned rows

__device__ __forceinline__ float bitsToF(unsigned int b) {
    union { unsigned int u; float f; } v; v.u = b << 16; return v.f;
}
__device__ __forceinline__ u16 f2bf(float f) {
    __hip_bfloat16 h = __float2bfloat16(f);
    return *reinterpret_cast<u16*>(&h);
}
// 2-op leaky relu (f32): max(x, 0.01x) — exact for all finite x
__device__ __forceinline__ float lrelu(float v) {
    return fmaxf(v, LRELU_NS * v);
}
__device__ __forceinline__ u16 ldW(const void* p, int i, int isF32) {
    return isF32 ? f2bf(((const float*)p)[i]) : ((const u16*)p)[i];
}
__device__ __forceinline__ float ldF(const void* p, int i, int isF32) {
    return isF32 ? ((const float*)p)[i]
                 : bitsToF((unsigned int)((const u16*)p)[i]);
}
// float -> fp16 bits (native _Float16 cast = round-to-nearest-even)
__device__ __forceinline__ u16 f2h_bits(float f) {
    union { _Float16 h; u16 u; } v; v.h = (_Float16)f; return v.u;
}
// load -> fp16 bits (for the f16 pair path)
__device__ __forceinline__ u16 ldWh(const void* p, int i, int isF32) {
    float f = isF32 ? ((const float*)p)[i]
                    : bitsToF((unsigned int)((const u16*)p)[i]);
    return f2h_bits(f);
}
__device__ __forceinline__ half2v u2h2(unsigned int x) {
    union { unsigned int u; half2v h; } v; v.u = x; return v.h;
}
__device__ __forceinline__ unsigned int h22u(half2v x) {
    union { half2v h; unsigned int u; } v; v.h = x; return v.u;
}

// dtype probe (verified) — all threads of the block must call.
__device__ __forceinline__ int computeIsF32(const u16* y, int* cnt, int t) {
    if (t == 0) *cnt = 0;
    __syncthreads();
    if (t < 256) {
        u16 v = y[2 * t];
        int e = (v >> 7) & 0xFF;
        if (v == 0 || (e >= 96 && e < 160)) atomicAdd(cnt, 1);
    }
    __syncthreads();
    return (*cnt < 192) ? 1 : 0;
}

// ---------------------------------------------------------------------------
// Kernel 1: pack — verbatim R0 (verified).
// ---------------------------------------------------------------------------
__global__ __launch_bounds__(256) void pack_kernel(
    const void* __restrict__ yhat,
    const void* __restrict__ Ws1, const void* __restrict__ Wc1,
    const void* __restrict__ Wb1, const void* __restrict__ Ws2,
    const void* __restrict__ Wc2,
    const void* __restrict__ bs1, const void* __restrict__ bc1,
    const void* __restrict__ bb1, const void* __restrict__ bs2,
    const void* __restrict__ bc2, const void* __restrict__ bb2,
    u16* __restrict__ WallT, u16* __restrict__ W2T, float* __restrict__ biasF)
{
    __shared__ int fcnt;
    const int bid = blockIdx.x, t = threadIdx.x;
    const int isF32 = computeIsF32((const u16*)yhat, &fcnt, t);
    if (bid < 64) {
        __shared__ u16 tile[64][65];
        const int c0 = (bid & 15) * 64;      // col-tile in [0,1024)
        const int k0 = (bid >> 4) * 64;      // k-tile in [0,256)
        const void* src; int coff; int roff = 0;
        if (c0 < 256)      { src = Ws1; coff = c0; }
        else if (c0 < 512) { src = Wc1; coff = c0 - 256; }
        else if (c0 < 768) { src = Wb1; coff = c0 - 512; }
        else               { src = Wb1; coff = c0 - 768; roff = 256; }
        const int cc = t & 63, kk0 = t >> 6;
        #pragma unroll
        for (int i = 0; i < 16; ++i) {
            int kk = kk0 + i * 4;
            tile[kk][cc] = ldW(src, (k0 + kk + roff) * 256 + coff + cc, isF32);
        }
        __syncthreads();
        const int kk2 = t & 63, cc0 = t >> 6;
        #pragma unroll
        for (int i = 0; i < 16; ++i) {
            int cc2 = cc0 + i * 4;
            WallT[(c0 + cc2) * 256 + (k0 + kk2)] = tile[kk2][cc2];
        }
    } else if (bid < 128) {
        int e2 = (bid - 64) * 256 + t;       // < 16384
        int c = e2 >> 8, k = e2 & 255;
        u16 v = 0;
        if (c < 40)                 v = ldW(Ws2, k * 40 + c, isF32);
        else if (c >= 48 && c < 53) v = ldW(Wc2, k * 5 + (c - 48), isF32);
        W2T[c * 256 + k] = v;
    } else {
        int idx = (bid - 128) * 256 + t;     // < 1024
        float v = 0.f;
        if (idx < 256)       v = ldF(bs1, idx, isF32);
        else if (idx < 512)  v = ldF(bc1, idx - 256, isF32);
        else if (idx < 768)  v = ldF(bb1, idx - 512, isF32);
        else if (idx < 808)  v = ldF(bs2, idx - 768, isF32);
        else if (idx < 813)  v = ldF(bc2, idx - 808, isF32);
        else if (idx >= 816 && idx < 821) v = ldF(bb2, idx - 816, isF32);
        biasF[idx] = v;
    }
}

// ---------------------------------------------------------------------------
// Kernel 2: fused — exact R10 structure (X staged in LDS; 2 blocks/CU), with
// ONE delta: the bonds pair phase runs the wave's jobs TWO AT A TIME
// (independent acc chains / LDS reads, shared wf) for ILP on the
// ds_read -> packed-VALU -> MFMA critical path. Per-job math, ks order,
// and stores are bit-identical to R10 (pure cross-job reordering).
//   bid in [0,512):   bonds body (R10) — mol = bid>>1, half = bid&1.
//   bid in [512,832): heads body (R10/R5, verbatim).
// LDS = union(78.7 KB bonds, 67.6 KB heads) -> 2 blocks/CU (as R10).
// ---------------------------------------------------------------------------
union SharedHB {
    struct { u16 Xs[64 * SK]; u16 Hb[64 * SK]; } hd;                        // 67584 B
    struct { u16 Xm[48 * SK]; u16 P1L[48 * SK]; u16 P2L[48 * SK];
             u16 WsB[5 * 264]; } bd;                                       // 78672 B
};

__global__ __launch_bounds__(512) void fused_kernel(
    const void* __restrict__ Xv, const u16* __restrict__ WallT,
    const u16* __restrict__ W2T, const void* __restrict__ Wb2,
    const float* __restrict__ biasF, void* __restrict__ outv)
{
    __shared__ SharedHB sh;
    __shared__ int fcnt;
    const int t = threadIdx.x;
    const int bid = blockIdx.x;
    const int isF32 = computeIsF32((const u16*)Xv, &fcnt, t);

    const int w = t >> 6, l = t & 63;
    const int ml = l & 15, kq = l >> 4, r0 = kq * 4;

    if (bid < 512) {
        // =================== bonds body (R10) ===================
        const int b = bid >> 1;            // molecule
        const int h = bid & 1;             // job half

        if (isF32) {   // stage X rows 0..39 (fp32 -> bf16), zero rows 40..47
            const floatx4* __restrict__ src = (const floatx4*)((const float*)Xv + b * 10240);
            #pragma unroll
            for (int s = 0; s < 5; ++s) {
                int cid = t + s * 512;             // 2560 chunks of 4 floats
                int row = cid >> 6, ch = cid & 63;
                floatx4 f = src[cid];
                ushort4v u;
                u[0] = f2bf(f[0]); u[1] = f2bf(f[1]); u[2] = f2bf(f[2]); u[3] = f2bf(f[3]);
                *(ushort4v*)&sh.bd.Xm[row * SK + ch * 4] = u;
            }
            {   // zero rows 40..47
                int row = 40 + (t >> 6), ch = t & 63;
                ushort4v z = {0, 0, 0, 0};
                *(ushort4v*)&sh.bd.Xm[row * SK + ch * 4] = z;
            }
        } else {
            const int4v* __restrict__ src = (const int4v*)((const u16*)Xv + b * 10240);
            #pragma unroll
            for (int s = 0; s < 3; ++s) {
                int cid = t + s * 512;             // < 1536
                int row = cid >> 5, ch = cid & 31;
                if (cid < 1280) *(int4v*)&sh.bd.Xm[row * SK + ch * 8] = src[cid];
                else { int4v z = {0, 0, 0, 0}; *(int4v*)&sh.bd.Xm[row * SK + ch * 8] = z; }
            }
        }
        // Wb2[256][5] -> WsB[c][k] fp16, c<5
        #pragma unroll
        for (int s = 0; s < 3; ++s) {
            int e2 = t + s * 512;                  // < 1536
            if (e2 < 1280) {
                int c = e2 >> 8, k = e2 & 255;
                sh.bd.WsB[c * 264 + k] = ldWh(Wb2, k * 5 + c, isF32);
            }
        }
        __syncthreads();   // Xm + WsB visible

        // ---- layer 1 (R10): P = X @ Wb1 (+bb1 on P1), fp16 out ----
        for (int n = 0; n < 4; ++n) {
            const int gc = (w + 8 * n) * 16 + ml;  // [0,512)
            floatx4 acc[3] = {};
            #pragma unroll
            for (int ks = 0; ks < 8; ++ks) {
                const int k0 = ks * 32 + kq * 8;
                bf16x8 bf = *(const bf16x8*)&WallT[(512 + gc) * 256 + k0];
                #pragma unroll
                for (int i = 0; i < 3; ++i) {
                    bf16x8 a = *(const bf16x8*)&sh.bd.Xm[(i * 16 + ml) * SK + k0];
                    acc[i] = __builtin_amdgcn_mfma_f32_16x16x32_bf16(a, bf, acc[i], 0, 0, 0);
                }
            }
            u16* dst = (gc < 256) ? sh.bd.P1L : sh.bd.P2L;
            const int col = gc & 255;
            const float bias = (gc < 256) ? biasF[512 + gc] : 0.f;   // bb1 on P1
            #pragma unroll
            for (int i = 0; i < 3; ++i)
                #pragma unroll
                for (int r = 0; r < 4; ++r)
                    dst[(i * 16 + r0 + r) * SK + col] = f2h_bits(acc[i][r] + bias);
        }
        __syncthreads();

        // ---- symmetric-fused pair phase, packed f16, jobs 2-at-a-time ----
        const int sel = (ml < 5) ? ml : 4;         // ml>=5 feeds discarded D cols
        half8 wf[8];
        #pragma unroll
        for (int ks = 0; ks < 8; ++ks)
            wf[ks] = *(const half8*)&sh.bd.WsB[sel * 264 + ks * 32 + kq * 8];
        const float b2x2 = 2.f * biasF[816 + ml];  // ml>=5 reads zeros (in-bounds)
        const _Float16 c001 = (_Float16)0.01f;

        // per-job af+mfma step (identical math to R10's inner body)
        auto stepJob = [&](int i, int jt, int ks, floatx4& acc) {
            const int k0 = ks * 32 + kq * 8;
            const uint4v a1 = *(const uint4v*)&sh.bd.P1L[i * SK + k0];
            const uint4v a2 = *(const uint4v*)&sh.bd.P2L[i * SK + k0];
            const uint4v b1 = *(const uint4v*)&sh.bd.P1L[(jt * 16 + ml) * SK + k0];
            const uint4v b2 = *(const uint4v*)&sh.bd.P2L[(jt * 16 + ml) * SK + k0];
            union { unsigned int u[4]; half8 v; } af;
            #pragma unroll
            for (int d = 0; d < 4; ++d) {
                const half2v tF = u2h2(a1[d]) + u2h2(b2[d]);   // v_pk_add_f16
                const half2v tB = u2h2(b1[d]) + u2h2(a2[d]);
                const half2v lF = __builtin_elementwise_max(tF, tF * c001);
                const half2v lB = __builtin_elementwise_max(tB, tB * c001);
                af.u[d] = h22u(lF + lB);
            }
            acc = __builtin_amdgcn_mfma_f32_16x16x32_f16(af.v, wf[ks], acc, 0, 0, 0);
        };
        // per-job store (identical to R10)
        auto storeJob = [&](int i, int jt, const floatx4& acc) {
            if (ml < 5) {                          // D: row=kq*4+r -> j, col=ml -> class
                const bool diag = (jt == (i >> 4));
                #pragma unroll
                for (int r = 0; r < 4; ++r) {
                    const int j = jt * 16 + r0 + r;
                    if (j < 40 && (!diag || j >= i)) {
                        const float v = acc[r] + b2x2;
                        const int o1 = 460800 + (b * 1600 + i * 40 + j) * 5 + ml;
                        if (isF32) ((float*)outv)[o1] = v;
                        else ((__hip_bfloat16*)outv)[o1] = __float2bfloat16(v);
                        if (!diag || j > i) {
                            const int o2 = 460800 + (b * 1600 + j * 40 + i) * 5 + ml;
                            if (isF32) ((float*)outv)[o2] = v;
                            else ((__hip_bfloat16*)outv)[o2] = __float2bfloat16(v);
                        }
                    }
                }
            }
        };
        // two jobs interleaved: independent acc chains, shared wf
        auto pairJob = [&](const int mA, const int jtA,
                           const int mB, const int jtB, const bool doB) {
            const int iA = w + 8 * mA;
            const int iB = w + 8 * mB;
            floatx4 accA = {}, accB = {};
            #pragma unroll
            for (int ks = 0; ks < 8; ++ks) {
                stepJob(iA, jtA, ks, accA);
                if (doB) stepJob(iB, jtB, ks, accB);
            }
            storeJob(iA, jtA, accA);
            if (doB) storeJob(iB, jtB, accB);
        };

        // coverage (R10's 11 jobs, parity-split): h=0 even idx, h=1 odd idx.
        if (h == 0) {         // (0,0),(0,2),(1,1),(2,1),(3,1),(4,2)
            pairJob(0, 0, 0, 2, true);
            pairJob(1, 1, 2, 1, true);
            pairJob(3, 1, 4, 2, true);
        } else {              // (0,1),(1,0),(1,2),(2,2),(3,2)
            pairJob(0, 1, 1, 0, true);
            pairJob(1, 2, 2, 2, true);
            pairJob(3, 2, 3, 2, false);
        }
    } else {
        // =================== heads body (R10/R5, verbatim) ===================
        const int hb = bid - 512;
        const int bm0 = (hb % 160) * 64;
        const int head = hb / 160;

        if (isF32) {   // stage X tile [64][256] from fp32, cvt to bf16
            const floatx4* __restrict__ src = (const floatx4*)((const float*)Xv + bm0 * 256);
            #pragma unroll
            for (int s = 0; s < 8; ++s) {
                int cid = t + s * 512;             // < 4096 chunks of 4 floats
                int row = cid >> 6, ch = cid & 63;
                floatx4 f = src[cid];
                ushort4v u;
                u[0] = f2bf(f[0]); u[1] = f2bf(f[1]); u[2] = f2bf(f[2]); u[3] = f2bf(f[3]);
                *(ushort4v*)&sh.hd.Xs[row * SK + ch * 4] = u;
            }
        } else {       // stage X tile from bf16
            const int4v* __restrict__ src = (const int4v*)((const u16*)Xv + bm0 * 256);
            #pragma unroll
            for (int s = 0; s < 4; ++s) {
                int cid = t + s * 512;             // < 2048 chunks of 8 bf16
                int row = cid >> 5, ch = cid & 31;
                *(int4v*)&sh.hd.Xs[row * SK + ch * 8] = src[cid];
            }
        }
        __syncthreads();

        // ---- layer 1: 16 col-tiles over 8 waves; 4 M-tiles each ----
        #pragma unroll
        for (int n = 0; n < 2; ++n) {
            const int ct = w + 8 * n;              // [0,16)
            floatx4 acc[4] = {};
            #pragma unroll
            for (int ks = 0; ks < 8; ++ks) {
                const int k0 = ks * 32 + kq * 8;
                bf16x8 bf = *(const bf16x8*)&WallT[(head * 256 + ct * 16 + ml) * 256 + k0];
                #pragma unroll
                for (int mt = 0; mt < 4; ++mt) {
                    bf16x8 a = *(const bf16x8*)&sh.hd.Xs[(mt * 16 + ml) * SK + k0];
                    acc[mt] = __builtin_amdgcn_mfma_f32_16x16x32_bf16(a, bf, acc[mt], 0, 0, 0);
                }
            }
            const int col = ct * 16 + ml;          // [0,256)
            const float bias = biasF[head * 256 + col];   // bs1 | bc1
            #pragma unroll
            for (int mt = 0; mt < 4; ++mt)
                #pragma unroll
                for (int r = 0; r < 4; ++r)
                    sh.hd.Hb[(mt * 16 + r0 + r) * SK + col] = f2bf(lrelu(acc[mt][r] + bias));
        }
        __syncthreads();   // Hb complete

        // ---- layer 2: waves 0..3 own M-tile w ----
        if (w < 4) {
            const int nct = (head == 0) ? 3 : 1;   // block-uniform
            const int c0  = (head == 0) ? 0 : 48;
            floatx4 acc2[3] = {};
            #pragma unroll
            for (int ks = 0; ks < 8; ++ks) {
                const int k0 = ks * 32 + kq * 8;
                bf16x8 a = *(const bf16x8*)&sh.hd.Hb[(w * 16 + ml) * SK + k0];
                #pragma unroll
                for (int j = 0; j < 3; ++j) {
                    if (j < nct) {
                        bf16x8 bf = *(const bf16x8*)&W2T[(c0 + j * 16 + ml) * 256 + k0];
                        acc2[j] = __builtin_amdgcn_mfma_f32_16x16x32_bf16(a, bf, acc2[j], 0, 0, 0);
                    }
                }
            }
            #pragma unroll
            for (int j = 0; j < 3; ++j) {
                if (j < nct) {
                    const int col = j * 16 + ml;
                    const int lim = (head == 0) ? 40 : 5;
                    if (col < lim) {
                        const float bias = biasF[(head == 0 ? 768 : 808) + col];
                        #pragma unroll
                        for (int r = 0; r < 4; ++r) {
                            const int row = bm0 + w * 16 + r0 + r;
                            const int o = (head == 0) ? row * 40 + col
                                                      : 409600 + row * 5 + col;
                            const float v = acc2[j][r] + bias;
                            if (isF32) ((float*)outv)[o] = v;
                            else ((__hip_bfloat16*)outv)[o] = __float2bfloat16(v);
                        }
                    }
                }
            }
        }
    }
}

// ---------------------------------------------------------------------------
extern "C" void kernel_launch(void* const* d_in, const int* in_sizes, int n_in,
                              void* d_out, int out_size, void* d_ws, size_t ws_size,
                              hipStream_t stream)
{
    const void* yhat = d_in[0];
    const void* Ws1  = d_in[1];
    const void* bs1  = d_in[2];
    const void* Ws2  = d_in[3];
    const void* bs2  = d_in[4];
    const void* Wc1  = d_in[5];
    const void* bc1  = d_in[6];
    const void* Wc2  = d_in[7];
    const void* bc2  = d_in[8];
    const void* Wb1  = d_in[9];
    const void* bb1  = d_in[10];
    const void* Wb2  = d_in[11];
    const void* bb2  = d_in[12];

    // workspace: 565248 bytes total (verified R0 layout)
    char* wsb = (char*)d_ws;
    float* biasF = (float*)(wsb + 4096);     // 1024 floats
    u16*   W2T   = (u16*)(wsb + 8192);       // 64*256 bf16  = 32768 B
    u16*   WallT = (u16*)(wsb + 40960);      // 1024*256 bf16 = 524288 B

    pack_kernel<<<132, 256, 0, stream>>>(yhat, Ws1, Wc1, Wb1, Ws2, Wc2,
                                         bs1, bc1, bb1, bs2, bc2, bb2,
                                         WallT, W2T, biasF);
    fused_kernel<<<832, 512, 0, stream>>>(yhat, WallT, W2T, Wb2, biasF, d_out);
}

// Round 16
// 131.453 us; speedup vs baseline: 1.9497x; 1.0125x over previous
//
#include <hip/hip_runtime.h>
#include <hip/hip_bf16.h>

typedef unsigned short u16;
typedef __attribute__((ext_vector_type(4))) int   int4v;
typedef __attribute__((ext_vector_type(4))) unsigned int uint4v;
typedef __attribute__((ext_vector_type(4))) unsigned short ushort4v;
typedef __attribute__((ext_vector_type(4))) float floatx4;
typedef __attribute__((ext_vector_type(8))) short bf16x8;
typedef _Float16 half8 __attribute__((ext_vector_type(8)));
typedef _Float16 half2v __attribute__((ext_vector_type(2)));

#define LRELU_NS 0.01f
#define SK 264   // LDS k-stride (u16 units): 256 + 8 pad, 16B-aligned rows

__device__ __forceinline__ float bitsToF(unsigned int b) {
    union { unsigned int u; float f; } v; v.u = b << 16; return v.f;
}
__device__ __forceinline__ u16 f2bf(float f) {
    __hip_bfloat16 h = __float2bfloat16(f);
    return *reinterpret_cast<u16*>(&h);
}
// 2-op leaky relu (f32): max(x, 0.01x) — exact for all finite x
__device__ __forceinline__ float lrelu(float v) {
    return fmaxf(v, LRELU_NS * v);
}
__device__ __forceinline__ u16 ldW(const void* p, int i, int isF32) {
    return isF32 ? f2bf(((const float*)p)[i]) : ((const u16*)p)[i];
}
__device__ __forceinline__ float ldF(const void* p, int i, int isF32) {
    return isF32 ? ((const float*)p)[i]
                 : bitsToF((unsigned int)((const u16*)p)[i]);
}
// float -> fp16 bits (native _Float16 cast = round-to-nearest-even)
__device__ __forceinline__ u16 f2h_bits(float f) {
    union { _Float16 h; u16 u; } v; v.h = (_Float16)f; return v.u;
}
// load -> fp16 bits (for the f16 pair path)
__device__ __forceinline__ u16 ldWh(const void* p, int i, int isF32) {
    float f = isF32 ? ((const float*)p)[i]
                    : bitsToF((unsigned int)((const u16*)p)[i]);
    return f2h_bits(f);
}
__device__ __forceinline__ half2v u2h2(unsigned int x) {
    union { unsigned int u; half2v h; } v; v.u = x; return v.h;
}
__device__ __forceinline__ unsigned int h22u(half2v x) {
    union { half2v h; unsigned int u; } v; v.h = x; return v.u;
}

// dtype probe (verified) — all threads of the block must call.
__device__ __forceinline__ int computeIsF32(const u16* y, int* cnt, int t) {
    if (t == 0) *cnt = 0;
    __syncthreads();
    if (t < 256) {
        u16 v = y[2 * t];
        int e = (v >> 7) & 0xFF;
        if (v == 0 || (e >= 96 && e < 160)) atomicAdd(cnt, 1);
    }
    __syncthreads();
    return (*cnt < 192) ? 1 : 0;
}

// ---------------------------------------------------------------------------
// Kernel 1: pack — verbatim R0 (verified).
// ---------------------------------------------------------------------------
__global__ __launch_bounds__(256) void pack_kernel(
    const void* __restrict__ yhat,
    const void* __restrict__ Ws1, const void* __restrict__ Wc1,
    const void* __restrict__ Wb1, const void* __restrict__ Ws2,
    const void* __restrict__ Wc2,
    const void* __restrict__ bs1, const void* __restrict__ bc1,
    const void* __restrict__ bb1, const void* __restrict__ bs2,
    const void* __restrict__ bc2, const void* __restrict__ bb2,
    u16* __restrict__ WallT, u16* __restrict__ W2T, float* __restrict__ biasF)
{
    __shared__ int fcnt;
    const int bid = blockIdx.x, t = threadIdx.x;
    const int isF32 = computeIsF32((const u16*)yhat, &fcnt, t);
    if (bid < 64) {
        __shared__ u16 tile[64][65];
        const int c0 = (bid & 15) * 64;      // col-tile in [0,1024)
        const int k0 = (bid >> 4) * 64;      // k-tile in [0,256)
        const void* src; int coff; int roff = 0;
        if (c0 < 256)      { src = Ws1; coff = c0; }
        else if (c0 < 512) { src = Wc1; coff = c0 - 256; }
        else if (c0 < 768) { src = Wb1; coff = c0 - 512; }
        else               { src = Wb1; coff = c0 - 768; roff = 256; }
        const int cc = t & 63, kk0 = t >> 6;
        #pragma unroll
        for (int i = 0; i < 16; ++i) {
            int kk = kk0 + i * 4;
            tile[kk][cc] = ldW(src, (k0 + kk + roff) * 256 + coff + cc, isF32);
        }
        __syncthreads();
        const int kk2 = t & 63, cc0 = t >> 6;
        #pragma unroll
        for (int i = 0; i < 16; ++i) {
            int cc2 = cc0 + i * 4;
            WallT[(c0 + cc2) * 256 + (k0 + kk2)] = tile[kk2][cc2];
        }
    } else if (bid < 128) {
        int e2 = (bid - 64) * 256 + t;       // < 16384
        int c = e2 >> 8, k = e2 & 255;
        u16 v = 0;
        if (c < 40)                 v = ldW(Ws2, k * 40 + c, isF32);
        else if (c >= 48 && c < 53) v = ldW(Wc2, k * 5 + (c - 48), isF32);
        W2T[c * 256 + k] = v;
    } else {
        int idx = (bid - 128) * 256 + t;     // < 1024
        float v = 0.f;
        if (idx < 256)       v = ldF(bs1, idx, isF32);
        else if (idx < 512)  v = ldF(bc1, idx - 256, isF32);
        else if (idx < 768)  v = ldF(bb1, idx - 512, isF32);
        else if (idx < 808)  v = ldF(bs2, idx - 768, isF32);
        else if (idx < 813)  v = ldF(bc2, idx - 808, isF32);
        else if (idx >= 816 && idx < 821) v = ldF(bb2, idx - 816, isF32);
        biasF[idx] = v;
    }
}

// ---------------------------------------------------------------------------
// Kernel 2: fused — R10 structure (X staged in LDS; 2 blocks/CU). Delta vs
// R10: the bonds pair phase groups jobs BY jt so the j-side b1/b2 LDS reads
// are loaded once per (jt,ks) and shared across the group's 2-5 independent
// acc chains (b-side reads 176 -> 48 per wave; 4-5-deep MFMA ILP free).
// Per-(i,jt) ks order, af math, and stores bit-identical to R10.
//   bid in [0,512):   bonds — mol = bid>>1; half: h=0 -> jt=2 group (5 jobs),
//                     h=1 -> jt=0 + jt=1 groups (6 jobs).
//   bid in [512,832): heads body (R10/R5, verbatim).
// LDS = union(78.7 KB bonds, 67.6 KB heads) -> 2 blocks/CU (as R10).
// ---------------------------------------------------------------------------
union SharedHB {
    struct { u16 Xs[64 * SK]; u16 Hb[64 * SK]; } hd;                        // 67584 B
    struct { u16 Xm[48 * SK]; u16 P1L[48 * SK]; u16 P2L[48 * SK];
             u16 WsB[5 * 264]; } bd;                                       // 78672 B
};

__global__ __launch_bounds__(512) void fused_kernel(
    const void* __restrict__ Xv, const u16* __restrict__ WallT,
    const u16* __restrict__ W2T, const void* __restrict__ Wb2,
    const float* __restrict__ biasF, void* __restrict__ outv)
{
    __shared__ SharedHB sh;
    __shared__ int fcnt;
    const int t = threadIdx.x;
    const int bid = blockIdx.x;
    const int isF32 = computeIsF32((const u16*)Xv, &fcnt, t);

    const int w = t >> 6, l = t & 63;
    const int ml = l & 15, kq = l >> 4, r0 = kq * 4;

    if (bid < 512) {
        // =================== bonds body ===================
        const int b = bid >> 1;            // molecule
        const int h = bid & 1;             // job half

        if (isF32) {   // stage X rows 0..39 (fp32 -> bf16), zero rows 40..47
            const floatx4* __restrict__ src = (const floatx4*)((const float*)Xv + b * 10240);
            #pragma unroll
            for (int s = 0; s < 5; ++s) {
                int cid = t + s * 512;             // 2560 chunks of 4 floats
                int row = cid >> 6, ch = cid & 63;
                floatx4 f = src[cid];
                ushort4v u;
                u[0] = f2bf(f[0]); u[1] = f2bf(f[1]); u[2] = f2bf(f[2]); u[3] = f2bf(f[3]);
                *(ushort4v*)&sh.bd.Xm[row * SK + ch * 4] = u;
            }
            {   // zero rows 40..47
                int row = 40 + (t >> 6), ch = t & 63;
                ushort4v z = {0, 0, 0, 0};
                *(ushort4v*)&sh.bd.Xm[row * SK + ch * 4] = z;
            }
        } else {
            const int4v* __restrict__ src = (const int4v*)((const u16*)Xv + b * 10240);
            #pragma unroll
            for (int s = 0; s < 3; ++s) {
                int cid = t + s * 512;             // < 1536
                int row = cid >> 5, ch = cid & 31;
                if (cid < 1280) *(int4v*)&sh.bd.Xm[row * SK + ch * 8] = src[cid];
                else { int4v z = {0, 0, 0, 0}; *(int4v*)&sh.bd.Xm[row * SK + ch * 8] = z; }
            }
        }
        // Wb2[256][5] -> WsB[c][k] fp16, c<5
        #pragma unroll
        for (int s = 0; s < 3; ++s) {
            int e2 = t + s * 512;                  // < 1536
            if (e2 < 1280) {
                int c = e2 >> 8, k = e2 & 255;
                sh.bd.WsB[c * 264 + k] = ldWh(Wb2, k * 5 + c, isF32);
            }
        }
        __syncthreads();   // Xm + WsB visible

        // ---- layer 1 (R10): P = X @ Wb1 (+bb1 on P1), fp16 out ----
        for (int n = 0; n < 4; ++n) {
            const int gc = (w + 8 * n) * 16 + ml;  // [0,512)
            floatx4 acc[3] = {};
            #pragma unroll
            for (int ks = 0; ks < 8; ++ks) {
                const int k0 = ks * 32 + kq * 8;
                bf16x8 bf = *(const bf16x8*)&WallT[(512 + gc) * 256 + k0];
                #pragma unroll
                for (int i = 0; i < 3; ++i) {
                    bf16x8 a = *(const bf16x8*)&sh.bd.Xm[(i * 16 + ml) * SK + k0];
                    acc[i] = __builtin_amdgcn_mfma_f32_16x16x32_bf16(a, bf, acc[i], 0, 0, 0);
                }
            }
            u16* dst = (gc < 256) ? sh.bd.P1L : sh.bd.P2L;
            const int col = gc & 255;
            const float bias = (gc < 256) ? biasF[512 + gc] : 0.f;   // bb1 on P1
            #pragma unroll
            for (int i = 0; i < 3; ++i)
                #pragma unroll
                for (int r = 0; r < 4; ++r)
                    dst[(i * 16 + r0 + r) * SK + col] = f2h_bits(acc[i][r] + bias);
        }
        __syncthreads();

        // ---- symmetric-fused pair phase, packed f16, jt-grouped ----
        const int sel = (ml < 5) ? ml : 4;         // ml>=5 feeds discarded D cols
        half8 wf[8];
        #pragma unroll
        for (int ks = 0; ks < 8; ++ks)
            wf[ks] = *(const half8*)&sh.bd.WsB[sel * 264 + ks * 32 + kq * 8];
        const float b2x2 = 2.f * biasF[816 + ml];  // ml>=5 reads zeros (in-bounds)
        const _Float16 c001 = (_Float16)0.01f;

        // per-job store (identical to R10)
        auto storeJob = [&](int i, int jt, const floatx4& acc) {
            if (ml < 5) {                          // D: row=kq*4+r -> j, col=ml -> class
                const bool diag = (jt == (i >> 4));
                #pragma unroll
                for (int r = 0; r < 4; ++r) {
                    const int j = jt * 16 + r0 + r;
                    if (j < 40 && (!diag || j >= i)) {
                        const float v = acc[r] + b2x2;
                        const int o1 = 460800 + (b * 1600 + i * 40 + j) * 5 + ml;
                        if (isF32) ((float*)outv)[o1] = v;
                        else ((__hip_bfloat16*)outv)[o1] = __float2bfloat16(v);
                        if (!diag || j > i) {
                            const int o2 = 460800 + (b * 1600 + j * 40 + i) * 5 + ml;
                            if (isF32) ((float*)outv)[o2] = v;
                            else ((__hip_bfloat16*)outv)[o2] = __float2bfloat16(v);
                        }
                    }
                }
            }
        };

        // jt-group: b1/b2 loaded once per (jt,ks), shared across nm i-chains.
        // acc indices are compile-time (unrolled loop + guard) -> registers.
        auto runGroup = [&](const int jt, const int nm) {
            floatx4 acc[5] = {};
            #pragma unroll
            for (int ks = 0; ks < 8; ++ks) {
                const int k0 = ks * 32 + kq * 8;
                const uint4v b1 = *(const uint4v*)&sh.bd.P1L[(jt * 16 + ml) * SK + k0];
                const uint4v b2 = *(const uint4v*)&sh.bd.P2L[(jt * 16 + ml) * SK + k0];
                #pragma unroll
                for (int mm = 0; mm < 5; ++mm) {
                    if (mm < nm) {
                        const int i = w + 8 * mm;   // [0,40)
                        const uint4v a1 = *(const uint4v*)&sh.bd.P1L[i * SK + k0];
                        const uint4v a2 = *(const uint4v*)&sh.bd.P2L[i * SK + k0];
                        union { unsigned int u[4]; half8 v; } af;
                        #pragma unroll
                        for (int d = 0; d < 4; ++d) {
                            const half2v tF = u2h2(a1[d]) + u2h2(b2[d]);   // v_pk_add_f16
                            const half2v tB = u2h2(b1[d]) + u2h2(a2[d]);
                            const half2v lF = __builtin_elementwise_max(tF, tF * c001);
                            const half2v lB = __builtin_elementwise_max(tB, tB * c001);
                            af.u[d] = h22u(lF + lB);
                        }
                        acc[mm] = __builtin_amdgcn_mfma_f32_16x16x32_f16(af.v, wf[ks], acc[mm], 0, 0, 0);
                    }
                }
            }
            #pragma unroll
            for (int mm = 0; mm < 5; ++mm)
                if (mm < nm) storeJob(w + 8 * mm, jt, acc[mm]);
        };

        // coverage: jt=0 -> m{0,1}; jt=1 -> m{0..3}; jt=2 -> m{0..4}
        // (same 11-job multiset as R10; halves split by jt)
        if (h == 0) { runGroup(2, 5); }            // 5 jobs
        else        { runGroup(0, 2); runGroup(1, 4); }  // 6 jobs
    } else {
        // =================== heads body (R10/R5, verbatim) ===================
        const int hb = bid - 512;
        const int bm0 = (hb % 160) * 64;
        const int head = hb / 160;

        if (isF32) {   // stage X tile [64][256] from fp32, cvt to bf16
            const floatx4* __restrict__ src = (const floatx4*)((const float*)Xv + bm0 * 256);
            #pragma unroll
            for (int s = 0; s < 8; ++s) {
                int cid = t + s * 512;             // < 4096 chunks of 4 floats
                int row = cid >> 6, ch = cid & 63;
                floatx4 f = src[cid];
                ushort4v u;
                u[0] = f2bf(f[0]); u[1] = f2bf(f[1]); u[2] = f2bf(f[2]); u[3] = f2bf(f[3]);
                *(ushort4v*)&sh.hd.Xs[row * SK + ch * 4] = u;
            }
        } else {       // stage X tile from bf16
            const int4v* __restrict__ src = (const int4v*)((const u16*)Xv + bm0 * 256);
            #pragma unroll
            for (int s = 0; s < 4; ++s) {
                int cid = t + s * 512;             // < 2048 chunks of 8 bf16
                int row = cid >> 5, ch = cid & 31;
                *(int4v*)&sh.hd.Xs[row * SK + ch * 8] = src[cid];
            }
        }
        __syncthreads();

        // ---- layer 1: 16 col-tiles over 8 waves; 4 M-tiles each ----
        #pragma unroll
        for (int n = 0; n < 2; ++n) {
            const int ct = w + 8 * n;              // [0,16)
            floatx4 acc[4] = {};
            #pragma unroll
            for (int ks = 0; ks < 8; ++ks) {
                const int k0 = ks * 32 + kq * 8;
                bf16x8 bf = *(const bf16x8*)&WallT[(head * 256 + ct * 16 + ml) * 256 + k0];
                #pragma unroll
                for (int mt = 0; mt < 4; ++mt) {
                    bf16x8 a = *(const bf16x8*)&sh.hd.Xs[(mt * 16 + ml) * SK + k0];
                    acc[mt] = __builtin_amdgcn_mfma_f32_16x16x32_bf16(a, bf, acc[mt], 0, 0, 0);
                }
            }
            const int col = ct * 16 + ml;          // [0,256)
            const float bias = biasF[head * 256 + col];   // bs1 | bc1
            #pragma unroll
            for (int mt = 0; mt < 4; ++mt)
                #pragma unroll
                for (int r = 0; r < 4; ++r)
                    sh.hd.Hb[(mt * 16 + r0 + r) * SK + col] = f2bf(lrelu(acc[mt][r] + bias));
        }
        __syncthreads();   // Hb complete

        // ---- layer 2: waves 0..3 own M-tile w ----
        if (w < 4) {
            const int nct = (head == 0) ? 3 : 1;   // block-uniform
            const int c0  = (head == 0) ? 0 : 48;
            floatx4 acc2[3] = {};
            #pragma unroll
            for (int ks = 0; ks < 8; ++ks) {
                const int k0 = ks * 32 + kq * 8;
                bf16x8 a = *(const bf16x8*)&sh.hd.Hb[(w * 16 + ml) * SK + k0];
                #pragma unroll
                for (int j = 0; j < 3; ++j) {
                    if (j < nct) {
                        bf16x8 bf = *(const bf16x8*)&W2T[(c0 + j * 16 + ml) * 256 + k0];
                        acc2[j] = __builtin_amdgcn_mfma_f32_16x16x32_bf16(a, bf, acc2[j], 0, 0, 0);
                    }
                }
            }
            #pragma unroll
            for (int j = 0; j < 3; ++j) {
                if (j < nct) {
                    const int col = j * 16 + ml;
                    const int lim = (head == 0) ? 40 : 5;
                    if (col < lim) {
                        const float bias = biasF[(head == 0 ? 768 : 808) + col];
                        #pragma unroll
                        for (int r = 0; r < 4; ++r) {
                            const int row = bm0 + w * 16 + r0 + r;
                            const int o = (head == 0) ? row * 40 + col
                                                      : 409600 + row * 5 + col;
                            const float v = acc2[j][r] + bias;
                            if (isF32) ((float*)outv)[o] = v;
                            else ((__hip_bfloat16*)outv)[o] = __float2bfloat16(v);
                        }
                    }
                }
            }
        }
    }
}

// ---------------------------------------------------------------------------
extern "C" void kernel_launch(void* const* d_in, const int* in_sizes, int n_in,
                              void* d_out, int out_size, void* d_ws, size_t ws_size,
                              hipStream_t stream)
{
    const void* yhat = d_in[0];
    const void* Ws1  = d_in[1];
    const void* bs1  = d_in[2];
    const void* Ws2  = d_in[3];
    const void* bs2  = d_in[4];
    const void* Wc1  = d_in[5];
    const void* bc1  = d_in[6];
    const void* Wc2  = d_in[7];
    const void* bc2  = d_in[8];
    const void* Wb1  = d_in[9];
    const void* bb1  = d_in[10];
    const void* Wb2  = d_in[11];
    const void* bb2  = d_in[12];

    // workspace: 565248 bytes total (verified R0 layout)
    char* wsb = (char*)d_ws;
    float* biasF = (float*)(wsb + 4096);     // 1024 floats
    u16*   W2T   = (u16*)(wsb + 8192);       // 64*256 bf16  = 32768 B
    u16*   WallT = (u16*)(wsb + 40960);      // 1024*256 bf16 = 524288 B

    pack_kernel<<<132, 256, 0, stream>>>(yhat, Ws1, Wc1, Wb1, Ws2, Wc2,
                                         bs1, bc1, bb1, bs2, bc2, bb2,
                                         WallT, W2T, biasF);
    fused_kernel<<<832, 512, 0, stream>>>(yhat, WallT, W2T, Wb2, biasF, d_out);
}

// Round 17
// 122.740 us; speedup vs baseline: 2.0881x; 1.0710x over previous
//
#include <hip/hip_runtime.h>
#include <hip/hip_bf16.h>

typedef unsigned short u16;
typedef __attribute__((ext_vector_type(4))) int   int4v;
typedef __attribute__((ext_vector_type(4))) unsigned int uint4v;
typedef __attribute__((ext_vector_type(4))) unsigned short ushort4v;
typedef __attribute__((ext_vector_type(4))) float floatx4;
typedef __attribute__((ext_vector_type(8))) short bf16x8;
typedef _Float16 half8 __attribute__((ext_vector_type(8)));
typedef _Float16 half2v __attribute__((ext_vector_type(2)));

#define LRELU_NS 0.01f
#define SK 264   // LDS k-stride (u16 units): 256 + 8 pad, 16B-aligned rows

__device__ __forceinline__ float bitsToF(unsigned int b) {
    union { unsigned int u; float f; } v; v.u = b << 16; return v.f;
}
__device__ __forceinline__ u16 f2bf(float f) {
    __hip_bfloat16 h = __float2bfloat16(f);
    return *reinterpret_cast<u16*>(&h);
}
// 2-op leaky relu (f32): max(x, 0.01x) — exact for all finite x
__device__ __forceinline__ float lrelu(float v) {
    return fmaxf(v, LRELU_NS * v);
}
__device__ __forceinline__ u16 ldW(const void* p, int i, int isF32) {
    return isF32 ? f2bf(((const float*)p)[i]) : ((const u16*)p)[i];
}
__device__ __forceinline__ float ldF(const void* p, int i, int isF32) {
    return isF32 ? ((const float*)p)[i]
                 : bitsToF((unsigned int)((const u16*)p)[i]);
}
// float -> fp16 bits (native _Float16 cast = round-to-nearest-even)
__device__ __forceinline__ u16 f2h_bits(float f) {
    union { _Float16 h; u16 u; } v; v.h = (_Float16)f; return v.u;
}
// load -> fp16 bits (for the f16 pair path)
__device__ __forceinline__ u16 ldWh(const void* p, int i, int isF32) {
    float f = isF32 ? ((const float*)p)[i]
                    : bitsToF((unsigned int)((const u16*)p)[i]);
    return f2h_bits(f);
}
__device__ __forceinline__ half2v u2h2(unsigned int x) {
    union { unsigned int u; half2v h; } v; v.u = x; return v.h;
}
__device__ __forceinline__ unsigned int h22u(half2v x) {
    union { half2v h; unsigned int u; } v; v.h = x; return v.u;
}

// dtype probe (verified) — all threads of the block must call.
__device__ __forceinline__ int computeIsF32(const u16* y, int* cnt, int t) {
    if (t == 0) *cnt = 0;
    __syncthreads();
    if (t < 256) {
        u16 v = y[2 * t];
        int e = (v >> 7) & 0xFF;
        if (v == 0 || (e >= 96 && e < 160)) atomicAdd(cnt, 1);
    }
    __syncthreads();
    return (*cnt < 192) ? 1 : 0;
}

// ---------------------------------------------------------------------------
// Kernel 1: pack — verbatim R0 (verified).
// ---------------------------------------------------------------------------
__global__ __launch_bounds__(256) void pack_kernel(
    const void* __restrict__ yhat,
    const void* __restrict__ Ws1, const void* __restrict__ Wc1,
    const void* __restrict__ Wb1, const void* __restrict__ Ws2,
    const void* __restrict__ Wc2,
    const void* __restrict__ bs1, const void* __restrict__ bc1,
    const void* __restrict__ bb1, const void* __restrict__ bs2,
    const void* __restrict__ bc2, const void* __restrict__ bb2,
    u16* __restrict__ WallT, u16* __restrict__ W2T, float* __restrict__ biasF)
{
    __shared__ int fcnt;
    const int bid = blockIdx.x, t = threadIdx.x;
    const int isF32 = computeIsF32((const u16*)yhat, &fcnt, t);
    if (bid < 64) {
        __shared__ u16 tile[64][65];
        const int c0 = (bid & 15) * 64;      // col-tile in [0,1024)
        const int k0 = (bid >> 4) * 64;      // k-tile in [0,256)
        const void* src; int coff; int roff = 0;
        if (c0 < 256)      { src = Ws1; coff = c0; }
        else if (c0 < 512) { src = Wc1; coff = c0 - 256; }
        else if (c0 < 768) { src = Wb1; coff = c0 - 512; }
        else               { src = Wb1; coff = c0 - 768; roff = 256; }
        const int cc = t & 63, kk0 = t >> 6;
        #pragma unroll
        for (int i = 0; i < 16; ++i) {
            int kk = kk0 + i * 4;
            tile[kk][cc] = ldW(src, (k0 + kk + roff) * 256 + coff + cc, isF32);
        }
        __syncthreads();
        const int kk2 = t & 63, cc0 = t >> 6;
        #pragma unroll
        for (int i = 0; i < 16; ++i) {
            int cc2 = cc0 + i * 4;
            WallT[(c0 + cc2) * 256 + (k0 + kk2)] = tile[kk2][cc2];
        }
    } else if (bid < 128) {
        int e2 = (bid - 64) * 256 + t;       // < 16384
        int c = e2 >> 8, k = e2 & 255;
        u16 v = 0;
        if (c < 40)                 v = ldW(Ws2, k * 40 + c, isF32);
        else if (c >= 48 && c < 53) v = ldW(Wc2, k * 5 + (c - 48), isF32);
        W2T[c * 256 + k] = v;
    } else {
        int idx = (bid - 128) * 256 + t;     // < 1024
        float v = 0.f;
        if (idx < 256)       v = ldF(bs1, idx, isF32);
        else if (idx < 512)  v = ldF(bc1, idx - 256, isF32);
        else if (idx < 768)  v = ldF(bb1, idx - 512, isF32);
        else if (idx < 808)  v = ldF(bs2, idx - 768, isF32);
        else if (idx < 813)  v = ldF(bc2, idx - 808, isF32);
        else if (idx >= 816 && idx < 821) v = ldF(bb2, idx - 816, isF32);
        biasF[idx] = v;
    }
}

// ---------------------------------------------------------------------------
// Kernel 2: fused — R16 structure with ONE delta: one bonds block per
// MOLECULE (no half-split). Each bonds block runs all three jt-groups
// (union of R16's verified h=0/h=1 sets: same 11-job multiset, same math,
// disjoint stores). Kills the per-molecule L1+staging duplication (bonds
// L1 work halved globally) and improves slot fill (576 blocks vs 832 on
// 512 resident slots).
//   bid in [0,256):   bonds — mol = bid; jt-grouped pair phase (R16).
//   bid in [256,576): heads body (R10/R5, verbatim).
// LDS = union(78.7 KB bonds, 67.6 KB heads) -> 2 blocks/CU (as R10/R16).
// ---------------------------------------------------------------------------
union SharedHB {
    struct { u16 Xs[64 * SK]; u16 Hb[64 * SK]; } hd;                        // 67584 B
    struct { u16 Xm[48 * SK]; u16 P1L[48 * SK]; u16 P2L[48 * SK];
             u16 WsB[5 * 264]; } bd;                                       // 78672 B
};

__global__ __launch_bounds__(512) void fused_kernel(
    const void* __restrict__ Xv, const u16* __restrict__ WallT,
    const u16* __restrict__ W2T, const void* __restrict__ Wb2,
    const float* __restrict__ biasF, void* __restrict__ outv)
{
    __shared__ SharedHB sh;
    __shared__ int fcnt;
    const int t = threadIdx.x;
    const int bid = blockIdx.x;
    const int isF32 = computeIsF32((const u16*)Xv, &fcnt, t);

    const int w = t >> 6, l = t & 63;
    const int ml = l & 15, kq = l >> 4, r0 = kq * 4;

    if (bid < 256) {
        // =================== bonds body (1 block per molecule) ===================
        const int b = bid;                 // molecule

        if (isF32) {   // stage X rows 0..39 (fp32 -> bf16), zero rows 40..47
            const floatx4* __restrict__ src = (const floatx4*)((const float*)Xv + b * 10240);
            #pragma unroll
            for (int s = 0; s < 5; ++s) {
                int cid = t + s * 512;             // 2560 chunks of 4 floats
                int row = cid >> 6, ch = cid & 63;
                floatx4 f = src[cid];
                ushort4v u;
                u[0] = f2bf(f[0]); u[1] = f2bf(f[1]); u[2] = f2bf(f[2]); u[3] = f2bf(f[3]);
                *(ushort4v*)&sh.bd.Xm[row * SK + ch * 4] = u;
            }
            {   // zero rows 40..47
                int row = 40 + (t >> 6), ch = t & 63;
                ushort4v z = {0, 0, 0, 0};
                *(ushort4v*)&sh.bd.Xm[row * SK + ch * 4] = z;
            }
        } else {
            const int4v* __restrict__ src = (const int4v*)((const u16*)Xv + b * 10240);
            #pragma unroll
            for (int s = 0; s < 3; ++s) {
                int cid = t + s * 512;             // < 1536
                int row = cid >> 5, ch = cid & 31;
                if (cid < 1280) *(int4v*)&sh.bd.Xm[row * SK + ch * 8] = src[cid];
                else { int4v z = {0, 0, 0, 0}; *(int4v*)&sh.bd.Xm[row * SK + ch * 8] = z; }
            }
        }
        // Wb2[256][5] -> WsB[c][k] fp16, c<5
        #pragma unroll
        for (int s = 0; s < 3; ++s) {
            int e2 = t + s * 512;                  // < 1536
            if (e2 < 1280) {
                int c = e2 >> 8, k = e2 & 255;
                sh.bd.WsB[c * 264 + k] = ldWh(Wb2, k * 5 + c, isF32);
            }
        }
        __syncthreads();   // Xm + WsB visible

        // ---- layer 1 (R10): P = X @ Wb1 (+bb1 on P1), fp16 out ----
        for (int n = 0; n < 4; ++n) {
            const int gc = (w + 8 * n) * 16 + ml;  // [0,512)
            floatx4 acc[3] = {};
            #pragma unroll
            for (int ks = 0; ks < 8; ++ks) {
                const int k0 = ks * 32 + kq * 8;
                bf16x8 bf = *(const bf16x8*)&WallT[(512 + gc) * 256 + k0];
                #pragma unroll
                for (int i = 0; i < 3; ++i) {
                    bf16x8 a = *(const bf16x8*)&sh.bd.Xm[(i * 16 + ml) * SK + k0];
                    acc[i] = __builtin_amdgcn_mfma_f32_16x16x32_bf16(a, bf, acc[i], 0, 0, 0);
                }
            }
            u16* dst = (gc < 256) ? sh.bd.P1L : sh.bd.P2L;
            const int col = gc & 255;
            const float bias = (gc < 256) ? biasF[512 + gc] : 0.f;   // bb1 on P1
            #pragma unroll
            for (int i = 0; i < 3; ++i)
                #pragma unroll
                for (int r = 0; r < 4; ++r)
                    dst[(i * 16 + r0 + r) * SK + col] = f2h_bits(acc[i][r] + bias);
        }
        __syncthreads();

        // ---- symmetric-fused pair phase, packed f16, jt-grouped (R16) ----
        const int sel = (ml < 5) ? ml : 4;         // ml>=5 feeds discarded D cols
        half8 wf[8];
        #pragma unroll
        for (int ks = 0; ks < 8; ++ks)
            wf[ks] = *(const half8*)&sh.bd.WsB[sel * 264 + ks * 32 + kq * 8];
        const float b2x2 = 2.f * biasF[816 + ml];  // ml>=5 reads zeros (in-bounds)
        const _Float16 c001 = (_Float16)0.01f;

        // per-job store (identical to R10)
        auto storeJob = [&](int i, int jt, const floatx4& acc) {
            if (ml < 5) {                          // D: row=kq*4+r -> j, col=ml -> class
                const bool diag = (jt == (i >> 4));
                #pragma unroll
                for (int r = 0; r < 4; ++r) {
                    const int j = jt * 16 + r0 + r;
                    if (j < 40 && (!diag || j >= i)) {
                        const float v = acc[r] + b2x2;
                        const int o1 = 460800 + (b * 1600 + i * 40 + j) * 5 + ml;
                        if (isF32) ((float*)outv)[o1] = v;
                        else ((__hip_bfloat16*)outv)[o1] = __float2bfloat16(v);
                        if (!diag || j > i) {
                            const int o2 = 460800 + (b * 1600 + j * 40 + i) * 5 + ml;
                            if (isF32) ((float*)outv)[o2] = v;
                            else ((__hip_bfloat16*)outv)[o2] = __float2bfloat16(v);
                        }
                    }
                }
            }
        };

        // jt-group: b1/b2 loaded once per (jt,ks), shared across nm i-chains.
        auto runGroup = [&](const int jt, const int nm) {
            floatx4 acc[5] = {};
            #pragma unroll
            for (int ks = 0; ks < 8; ++ks) {
                const int k0 = ks * 32 + kq * 8;
                const uint4v b1 = *(const uint4v*)&sh.bd.P1L[(jt * 16 + ml) * SK + k0];
                const uint4v b2 = *(const uint4v*)&sh.bd.P2L[(jt * 16 + ml) * SK + k0];
                #pragma unroll
                for (int mm = 0; mm < 5; ++mm) {
                    if (mm < nm) {
                        const int i = w + 8 * mm;   // [0,40)
                        const uint4v a1 = *(const uint4v*)&sh.bd.P1L[i * SK + k0];
                        const uint4v a2 = *(const uint4v*)&sh.bd.P2L[i * SK + k0];
                        union { unsigned int u[4]; half8 v; } af;
                        #pragma unroll
                        for (int d = 0; d < 4; ++d) {
                            const half2v tF = u2h2(a1[d]) + u2h2(b2[d]);   // v_pk_add_f16
                            const half2v tB = u2h2(b1[d]) + u2h2(a2[d]);
                            const half2v lF = __builtin_elementwise_max(tF, tF * c001);
                            const half2v lB = __builtin_elementwise_max(tB, tB * c001);
                            af.u[d] = h22u(lF + lB);
                        }
                        acc[mm] = __builtin_amdgcn_mfma_f32_16x16x32_f16(af.v, wf[ks], acc[mm], 0, 0, 0);
                    }
                }
            }
            #pragma unroll
            for (int mm = 0; mm < 5; ++mm)
                if (mm < nm) storeJob(w + 8 * mm, jt, acc[mm]);
        };

        // all 11 jobs (union of R16's verified halves):
        // jt=0 -> m{0,1}; jt=1 -> m{0..3}; jt=2 -> m{0..4}
        runGroup(0, 2);
        runGroup(1, 4);
        runGroup(2, 5);
    } else {
        // =================== heads body (R10/R5, verbatim) ===================
        const int hb = bid - 256;
        const int bm0 = (hb % 160) * 64;
        const int head = hb / 160;

        if (isF32) {   // stage X tile [64][256] from fp32, cvt to bf16
            const floatx4* __restrict__ src = (const floatx4*)((const float*)Xv + bm0 * 256);
            #pragma unroll
            for (int s = 0; s < 8; ++s) {
                int cid = t + s * 512;             // < 4096 chunks of 4 floats
                int row = cid >> 6, ch = cid & 63;
                floatx4 f = src[cid];
                ushort4v u;
                u[0] = f2bf(f[0]); u[1] = f2bf(f[1]); u[2] = f2bf(f[2]); u[3] = f2bf(f[3]);
                *(ushort4v*)&sh.hd.Xs[row * SK + ch * 4] = u;
            }
        } else {       // stage X tile from bf16
            const int4v* __restrict__ src = (const int4v*)((const u16*)Xv + bm0 * 256);
            #pragma unroll
            for (int s = 0; s < 4; ++s) {
                int cid = t + s * 512;             // < 2048 chunks of 8 bf16
                int row = cid >> 5, ch = cid & 31;
                *(int4v*)&sh.hd.Xs[row * SK + ch * 8] = src[cid];
            }
        }
        __syncthreads();

        // ---- layer 1: 16 col-tiles over 8 waves; 4 M-tiles each ----
        #pragma unroll
        for (int n = 0; n < 2; ++n) {
            const int ct = w + 8 * n;              // [0,16)
            floatx4 acc[4] = {};
            #pragma unroll
            for (int ks = 0; ks < 8; ++ks) {
                const int k0 = ks * 32 + kq * 8;
                bf16x8 bf = *(const bf16x8*)&WallT[(head * 256 + ct * 16 + ml) * 256 + k0];
                #pragma unroll
                for (int mt = 0; mt < 4; ++mt) {
                    bf16x8 a = *(const bf16x8*)&sh.hd.Xs[(mt * 16 + ml) * SK + k0];
                    acc[mt] = __builtin_amdgcn_mfma_f32_16x16x32_bf16(a, bf, acc[mt], 0, 0, 0);
                }
            }
            const int col = ct * 16 + ml;          // [0,256)
            const float bias = biasF[head * 256 + col];   // bs1 | bc1
            #pragma unroll
            for (int mt = 0; mt < 4; ++mt)
                #pragma unroll
                for (int r = 0; r < 4; ++r)
                    sh.hd.Hb[(mt * 16 + r0 + r) * SK + col] = f2bf(lrelu(acc[mt][r] + bias));
        }
        __syncthreads();   // Hb complete

        // ---- layer 2: waves 0..3 own M-tile w ----
        if (w < 4) {
            const int nct = (head == 0) ? 3 : 1;   // block-uniform
            const int c0  = (head == 0) ? 0 : 48;
            floatx4 acc2[3] = {};
            #pragma unroll
            for (int ks = 0; ks < 8; ++ks) {
                const int k0 = ks * 32 + kq * 8;
                bf16x8 a = *(const bf16x8*)&sh.hd.Hb[(w * 16 + ml) * SK + k0];
                #pragma unroll
                for (int j = 0; j < 3; ++j) {
                    if (j < nct) {
                        bf16x8 bf = *(const bf16x8*)&W2T[(c0 + j * 16 + ml) * 256 + k0];
                        acc2[j] = __builtin_amdgcn_mfma_f32_16x16x32_bf16(a, bf, acc2[j], 0, 0, 0);
                    }
                }
            }
            #pragma unroll
            for (int j = 0; j < 3; ++j) {
                if (j < nct) {
                    const int col = j * 16 + ml;
                    const int lim = (head == 0) ? 40 : 5;
                    if (col < lim) {
                        const float bias = biasF[(head == 0 ? 768 : 808) + col];
                        #pragma unroll
                        for (int r = 0; r < 4; ++r) {
                            const int row = bm0 + w * 16 + r0 + r;
                            const int o = (head == 0) ? row * 40 + col
                                                      : 409600 + row * 5 + col;
                            const float v = acc2[j][r] + bias;
                            if (isF32) ((float*)outv)[o] = v;
                            else ((__hip_bfloat16*)outv)[o] = __float2bfloat16(v);
                        }
                    }
                }
            }
        }
    }
}

// ---------------------------------------------------------------------------
extern "C" void kernel_launch(void* const* d_in, const int* in_sizes, int n_in,
                              void* d_out, int out_size, void* d_ws, size_t ws_size,
                              hipStream_t stream)
{
    const void* yhat = d_in[0];
    const void* Ws1  = d_in[1];
    const void* bs1  = d_in[2];
    const void* Ws2  = d_in[3];
    const void* bs2  = d_in[4];
    const void* Wc1  = d_in[5];
    const void* bc1  = d_in[6];
    const void* Wc2  = d_in[7];
    const void* bc2  = d_in[8];
    const void* Wb1  = d_in[9];
    const void* bb1  = d_in[10];
    const void* Wb2  = d_in[11];
    const void* bb2  = d_in[12];

    // workspace: 565248 bytes total (verified R0 layout)
    char* wsb = (char*)d_ws;
    float* biasF = (float*)(wsb + 4096);     // 1024 floats
    u16*   W2T   = (u16*)(wsb + 8192);       // 64*256 bf16  = 32768 B
    u16*   WallT = (u16*)(wsb + 40960);      // 1024*256 bf16 = 524288 B

    pack_kernel<<<132, 256, 0, stream>>>(yhat, Ws1, Wc1, Wb1, Ws2, Wc2,
                                         bs1, bc1, bb1, bs2, bc2, bb2,
                                         WallT, W2T, biasF);
    fused_kernel<<<576, 512, 0, stream>>>(yhat, WallT, W2T, Wb2, biasF, d_out);
}